// Round 10
// baseline (305.293 us; speedup 1.0000x reference)
//
#include <hip/hip_runtime.h>
#include <hip/hip_bf16.h>
#include <math.h>

// GateFusion via bf16 MFMA (16x16x32). 2-phase async pipeline (T3-minimum):
// x staged global->LDS via __builtin_amdgcn_global_load_lds (zero VGPR cost --
// register prefetch was un-winnable: regalloc sank/spilled it in r3/4/6/7/9),
// double-buffered 32-row chunks, one barrier per iter. LDS reads XOR-swizzled
// (T2, both-sides: pre-swizzled DMA source + swizzled ds_read). Weights from
// L1/L2 in hoisted register batches. 128-thr blocks (2 waves), 40960B LDS ->
// 4 desynced blocks/CU.
// out = g * (x_d@W_d) + (1-g) * (x_c@W_c),
// g = sigmoid( relu(LN(concat@Wg1)) @ Wg2 ),  per row.
//
// d_ws: fragment-linear bf16 weights (see convert_weights):
//   frags 0..19 : Wg1  (ks 0..4) x (nt 0..3)   [K=160, N=64]
//   frags 20..59: [Wd;Wc] (ks 0..4) x (nt 0..7) [K=160, N=128]
// frag = 512 bf16: lane l holds B[k0+j][n], k0=ks*32+(l>>4)*8, n=nt*16+(l&15).

namespace {

typedef __attribute__((ext_vector_type(8))) short short8;
typedef __attribute__((ext_vector_type(4))) float f32x4;

constexpr int CD = 64, CC = 96, CH = 64, CF = 128;
constexpr int NFG1 = 20;
constexpr int NFRAG = 60;
constexpr int RPC  = 32;              // rows per chunk
constexpr int DBYT = RPC * CD * 4;    // 8192 B  (D region per buffer)
constexpr int CBYT = RPC * CC * 4;    // 12288 B (C region per buffer)
constexpr int CHKB = DBYT + CBYT;     // 20480 B per buffer

__device__ inline short bf16_of(float f) {
  __hip_bfloat16 h = __float2bfloat16(f);
  return *reinterpret_cast<short*>(&h);
}

__global__ void convert_weights(const float* __restrict__ Wd,
                                const float* __restrict__ Wc,
                                const float* __restrict__ Wg1,
                                short* __restrict__ ws) {
  const int t = blockIdx.x * 256 + threadIdx.x;
  if (t >= 64 * NFRAG) return;
  const int frag = t >> 6, l = t & 63;
  const int cidx = l & 15, kb = l >> 4;
  float v[8];
  if (frag < NFG1) {
    const int ks = frag >> 2, nt = frag & 3;
    const int n = nt * 16 + cidx, k0 = ks * 32 + kb * 8;
    #pragma unroll
    for (int j = 0; j < 8; ++j) v[j] = Wg1[(k0 + j) * CH + n];
  } else {
    const int f2 = frag - NFG1;
    const int ks = f2 >> 3, nt = f2 & 7;
    const int n = nt * 16 + cidx, k0 = ks * 32 + kb * 8;
    #pragma unroll
    for (int j = 0; j < 8; ++j) {
      const int k = k0 + j;
      v[j] = (k < CD) ? Wd[k * CF + n] : Wc[(k - CD) * CF + n];
    }
  }
  short8 o;
  #pragma unroll
  for (int j = 0; j < 8; ++j) o[j] = bf16_of(v[j]);
  *reinterpret_cast<short8*>(ws + frag * 512 + l * 8) = o;
}

typedef const __attribute__((address_space(1))) unsigned int GU;
typedef __attribute__((address_space(3))) unsigned int LU;

__device__ inline void dma16(const void* g, void* l) {
  __builtin_amdgcn_global_load_lds((GU*)g, (LU*)l, 16, 0, 0);
}

// Stage one 32-row chunk (row0 absolute) into LDS buffer at `buf`.
// Pre-swizzled source: LDS physical granule p holds global granule
// p ^ (row(p)&7) within its row, so swizzled reads see logical data.
__device__ inline void stage_chunk(const char* __restrict__ xdb,
                                   const char* __restrict__ xcb,
                                   int row0, char* buf, int tid) {
  const char* gD = xdb + (size_t)row0 * (CD * 4);
  char* wub0 = buf + ((tid & ~63) * 16);       // wave-uniform part of dest
  #pragma unroll
  for (int it = 0; it < 4; ++it) {             // D: 512 granules / 128 thr
    const int pg  = it * 128 + tid;
    const int row = pg >> 4;                   // 16 granules per 256B row
    const int lg  = pg ^ (row & 7);
    dma16(gD + (size_t)lg * 16, wub0 + it * 128 * 16);
  }
  const char* gC = xcb + (size_t)row0 * (CC * 4);
  char* wub1 = buf + DBYT + ((tid & ~63) * 16);
  #pragma unroll
  for (int it = 0; it < 6; ++it) {             // C: 768 granules / 128 thr
    const int pg  = it * 128 + tid;
    const int row = pg / 24;                   // 24 granules per 384B row
    const int u   = pg - row * 24;
    const int lg  = row * 24 + (u ^ (row & 7));
    dma16(gC + (size_t)lg * 16, wub1 + it * 128 * 16);
  }
}

__global__ __launch_bounds__(128, 2)
void gate_fusion_mfma(const float* __restrict__ xd,
                      const float* __restrict__ xc,
                      const float* __restrict__ gma,
                      const float* __restrict__ bta,
                      const float* __restrict__ Wg2,
                      const short* __restrict__ wf,
                      float* __restrict__ out,
                      int q, int rr) {
  __shared__ char lds[2][CHKB];

  const int tid  = threadIdx.x;
  const int lane = tid & 63;
  const int wv   = tid >> 6;                 // 0..1
  const int cidx = lane & 15;
  const int kb   = lane >> 4;
  const int b    = blockIdx.x;
  const int start = b * q + (b < rr ? b : rr);   // first chunk
  const int cnt   = q + (b < rr ? 1 : 0);        // chunks this block

  const char* xdb = (const char*)xd;
  const char* xcb = (const char*)xc;

  // per-wave constants
  float gmv[4], btv[4], w2v[4];
  #pragma unroll
  for (int nt = 0; nt < 4; ++nt) {
    const int c = nt * 16 + cidx;
    gmv[nt] = gma[c]; btv[nt] = bta[c]; w2v[nt] = Wg2[c];
  }

  const f32x4 vzero = {0.f, 0.f, 0.f, 0.f};
  const int lr = wv * 16 + cidx;             // LDS row this lane reads
  const int sw = (lr & 7) << 4;              // read-side XOR swizzle

  // prologue: stage chunk 0
  stage_chunk(xdb, xcb, start * RPC, lds[0], tid);
  __syncthreads();

  for (int t = 0; t < cnt; ++t) {
    // issue next chunk's DMA into the other buffer (in flight under compute)
    if (t + 1 < cnt)
      stage_chunk(xdb, xcb, (start + t + 1) * RPC, lds[(t + 1) & 1], tid);

    char* bD = lds[t & 1];
    char* bC = lds[t & 1] + DBYT;
    const int row0 = (start + t) * RPC;

    // ---- x A-fragments from LDS (swizzled ds_read_b128) -> bf16
    short8 xf[5];
    #pragma unroll
    for (int ks = 0; ks < 5; ++ks) {
      f32x4 lo, hi;
      if (ks < 2) {
        const int base = lr * 256 + ks * 128 + kb * 32;
        lo = *reinterpret_cast<const f32x4*>(bD + (base ^ sw));
        hi = *reinterpret_cast<const f32x4*>(bD + ((base + 16) ^ sw));
      } else {
        const int base = lr * 384 + (ks - 2) * 128 + kb * 32;
        lo = *reinterpret_cast<const f32x4*>(bC + (base ^ sw));
        hi = *reinterpret_cast<const f32x4*>(bC + ((base + 16) ^ sw));
      }
      short8 f;
      #pragma unroll
      for (int j = 0; j < 4; ++j) { f[j] = bf16_of(lo[j]); f[4 + j] = bf16_of(hi[j]); }
      xf[ks] = f;
    }

    // ---- phase 1: h = x @ Wg1 (weights hoisted in one 20-load burst)
    short8 wg[5][4];
    #pragma unroll
    for (int ks = 0; ks < 5; ++ks)
      #pragma unroll
      for (int nt = 0; nt < 4; ++nt)
        wg[ks][nt] = *reinterpret_cast<const short8*>(wf + (ks * 4 + nt) * 512 + lane * 8);

    f32x4 acc1[4];
    #pragma unroll
    for (int nt = 0; nt < 4; ++nt) acc1[nt] = vzero;
    #pragma unroll
    for (int ks = 0; ks < 5; ++ks)
      #pragma unroll
      for (int nt = 0; nt < 4; ++nt)
        acc1[nt] = __builtin_amdgcn_mfma_f32_16x16x32_bf16(
            xf[ks], wg[ks][nt], acc1[nt], 0, 0, 0);

    // ---- LayerNorm + relu + dot(Wg2) + sigmoid
    float gate[4];
    {
      float s[4], qq[4];
      #pragma unroll
      for (int r = 0; r < 4; ++r) {
        s[r] = 0.f; qq[r] = 0.f;
        #pragma unroll
        for (int nt = 0; nt < 4; ++nt) {
          const float c = acc1[nt][r];
          s[r] += c; qq[r] += c * c;
        }
      }
      #pragma unroll
      for (int m = 1; m < 16; m <<= 1)
        #pragma unroll
        for (int r = 0; r < 4; ++r) {
          s[r]  += __shfl_xor(s[r],  m, 64);
          qq[r] += __shfl_xor(qq[r], m, 64);
        }
      float p[4];
      #pragma unroll
      for (int r = 0; r < 4; ++r) {
        const float mu  = s[r] * (1.f / CH);
        const float var = qq[r] * (1.f / CH) - mu * mu;
        const float rsd = rsqrtf(var + 1e-5f);
        float pp = 0.f;
        #pragma unroll
        for (int nt = 0; nt < 4; ++nt) {
          const float h = fmaxf((acc1[nt][r] - mu) * rsd * gmv[nt] + btv[nt], 0.f);
          pp += h * w2v[nt];
        }
        p[r] = pp;
      }
      #pragma unroll
      for (int m = 1; m < 16; m <<= 1)
        #pragma unroll
        for (int r = 0; r < 4; ++r) p[r] += __shfl_xor(p[r], m, 64);
      #pragma unroll
      for (int r = 0; r < 4; ++r) gate[r] = 1.f / (1.f + expf(-p[r]));
    }

    // ---- phase 2 in 4 nt-quarter slices (weights hoisted per slice)
    #pragma unroll
    for (int qs = 0; qs < 4; ++qs) {
      short8 wb[5][2];
      #pragma unroll
      for (int ks = 0; ks < 5; ++ks)
        #pragma unroll
        for (int nt = 0; nt < 2; ++nt)
          wb[ks][nt] = *reinterpret_cast<const short8*>(
              wf + (NFG1 + ks * 8 + qs * 2 + nt) * 512 + lane * 8);

      f32x4 aD[2], aC[2];
      #pragma unroll
      for (int nt = 0; nt < 2; ++nt) { aD[nt] = vzero; aC[nt] = vzero; }
      #pragma unroll
      for (int ks = 0; ks < 5; ++ks) {
        if (ks < 2) {
          #pragma unroll
          for (int nt = 0; nt < 2; ++nt)
            aD[nt] = __builtin_amdgcn_mfma_f32_16x16x32_bf16(
                xf[ks], wb[ks][nt], aD[nt], 0, 0, 0);
        } else {
          #pragma unroll
          for (int nt = 0; nt < 2; ++nt)
            aC[nt] = __builtin_amdgcn_mfma_f32_16x16x32_bf16(
                xf[ks], wb[ks][nt], aC[nt], 0, 0, 0);
        }
      }

      const size_t rowb = (size_t)row0 + wv * 16 + kb * 4;
      #pragma unroll
      for (int nt = 0; nt < 2; ++nt) {
        #pragma unroll
        for (int r = 0; r < 4; ++r) {
          const float g = gate[r];
          const float o = fmaf(g, aD[nt][r] - aC[nt][r], aC[nt][r]);
          out[(rowb + r) * CF + (qs * 2 + nt) * 16 + cidx] = o;
        }
      }
    }

    __syncthreads();   // drains vmcnt (DMA t+1 complete) + re-syncs buffers
  }
}

}  // namespace

extern "C" void kernel_launch(void* const* d_in, const int* in_sizes, int n_in,
                              void* d_out, int out_size, void* d_ws, size_t ws_size,
                              hipStream_t stream) {
  const float* xd  = (const float*)d_in[0];
  const float* xc  = (const float*)d_in[1];
  const float* Wd  = (const float*)d_in[2];
  const float* Wc  = (const float*)d_in[3];
  const float* Wg1 = (const float*)d_in[4];
  const float* gma = (const float*)d_in[5];
  const float* bta = (const float*)d_in[6];
  const float* Wg2 = (const float*)d_in[7];
  float* out = (float*)d_out;
  short* ws  = (short*)d_ws;   // needs 60 KB

  const int N = in_sizes[0] / CD;
  const int nChunks = N / RPC;            // N % 32 == 0 -> 15625 exact

  convert_weights<<<dim3(15), dim3(256), 0, stream>>>(Wd, Wc, Wg1, ws);

  const int nblk = 1024;                  // 4 blocks/CU
  const int q  = nChunks / nblk;
  const int rr = nChunks - q * nblk;
  gate_fusion_mfma<<<dim3(nblk), dim3(128), 0, stream>>>(
      xd, xc, gma, bta, Wg2, ws, out, q, rr);
}

// Round 11
// 136.600 us; speedup vs baseline: 2.2349x; 2.2349x over previous
//
#include <hip/hip_runtime.h>
#include <hip/hip_bf16.h>
#include <math.h>

// GateFusion via bf16 MFMA (16x16x32). Round-9 structure (best: 134.7us,
// exact HBM traffic) + forced load-burst clustering: asm-liveness on all 10
// x-load destinations before the barrier so regalloc cannot sink/serialize
// the loads (r9's VGPR=40 proved it interleaved load->convert pairs, exposing
// ~4 HBM round-trips/wave -> 2.77 TB/s wall). All 10 loads in flight = 1
// round-trip/wave; ~20+ waves/CU x 10KB outstanding >> 22KB latency-BW need.
// global_load_lds DMA rejected: r10 showed intra-pass over-fetch (557MB).
// out = g * (x_d@W_d) + (1-g) * (x_c@W_c),
// g = sigmoid( relu(LN(concat@Wg1)) @ Wg2 ),  per row.
//
// d_ws: fragment-linear bf16 weights (see convert_weights):
//   frags 0..19 : Wg1  (ks 0..4) x (nt 0..3)   [K=160, N=64]
//   frags 20..59: [Wd;Wc] (ks 0..4) x (nt 0..7) [K=160, N=128]
// frag = 512 bf16: lane l holds B[k0+j][n], k0=ks*32+(l>>4)*8, n=nt*16+(l&15).

namespace {

typedef __attribute__((ext_vector_type(8))) short short8;
typedef __attribute__((ext_vector_type(4))) float f32x4;

constexpr int CD = 64, CC = 96, CH = 64, CF = 128;
constexpr int NFG1 = 20;   // gate-weight frags (read from L2/L3)
constexpr int NFCB = 40;   // combined-output-weight frags (staged in LDS)
constexpr int NFRAG = NFG1 + NFCB;
constexpr int WCHUNKS = NFCB * 512 * 2 / 16;  // 2560 x 16B = 40960 B

__device__ inline short bf16_of(float f) {
  __hip_bfloat16 h = __float2bfloat16(f);
  return *reinterpret_cast<short*>(&h);
}

__global__ void convert_weights(const float* __restrict__ Wd,
                                const float* __restrict__ Wc,
                                const float* __restrict__ Wg1,
                                short* __restrict__ ws) {
  const int t = blockIdx.x * 256 + threadIdx.x;
  if (t >= 64 * NFRAG) return;
  const int frag = t >> 6, l = t & 63;
  const int cidx = l & 15, kb = l >> 4;
  float v[8];
  if (frag < NFG1) {
    const int ks = frag >> 2, nt = frag & 3;
    const int n = nt * 16 + cidx, k0 = ks * 32 + kb * 8;
    #pragma unroll
    for (int j = 0; j < 8; ++j) v[j] = Wg1[(k0 + j) * CH + n];
  } else {
    const int f2 = frag - NFG1;
    const int ks = f2 >> 3, nt = f2 & 7;
    const int n = nt * 16 + cidx, k0 = ks * 32 + kb * 8;
    #pragma unroll
    for (int j = 0; j < 8; ++j) {
      const int k = k0 + j;
      v[j] = (k < CD) ? Wd[k * CF + n] : Wc[(k - CD) * CF + n];
    }
  }
  short8 o;
  #pragma unroll
  for (int j = 0; j < 8; ++j) o[j] = bf16_of(v[j]);
  *reinterpret_cast<short8*>(ws + frag * 512 + l * 8) = o;
}

__global__ __launch_bounds__(512, 4)
void gate_fusion_mfma(const float* __restrict__ xd,
                      const float* __restrict__ xc,
                      const float* __restrict__ gma,
                      const float* __restrict__ bta,
                      const float* __restrict__ Wg2,
                      const short* __restrict__ wf,
                      float* __restrict__ out, int N) {
  __shared__ short wlds[NFCB * 512];

  const int tid  = threadIdx.x;
  const int lane = tid & 63;
  const int wv   = tid >> 6;                 // 0..7
  const int r0   = blockIdx.x * 128 + wv * 16;   // 16 rows per wave
  const int cidx = lane & 15;
  const int kb   = lane >> 4;
  const bool active = (r0 < N);              // N % 16 == 0: whole-wave granularity

  // ---- issue this wave's x loads first (in flight under staging+barrier)
  f32x4 buf[5][2];
  if (active) {
    const size_t row = (size_t)(r0 + cidx);
    const float* rd = xd + row * CD + kb * 8;
    const float* rc = xc + row * CC + kb * 8;
    #pragma unroll
    for (int ks = 0; ks < 5; ++ks) {
      const float* p = (ks < 2) ? (rd + ks * 32) : (rc + (ks - 2) * 32);
      buf[ks][0] = *reinterpret_cast<const f32x4*>(p);
      buf[ks][1] = *reinterpret_cast<const f32x4*>(p + 4);
    }
  }

  // ---- stage the 40 output-weight frags (40960 B) into LDS
  {
    const short* wsrc = wf + NFG1 * 512;
    #pragma unroll
    for (int it = 0; it < WCHUNKS / 512; ++it) {
      const int c = tid + it * 512;
      short8 v = *reinterpret_cast<const short8*>(wsrc + (size_t)c * 8);
      *reinterpret_cast<short8*>(&wlds[c * 8]) = v;
    }
  }

  // ---- force all 10 load destinations simultaneously live: regalloc cannot
  // sink/serialize the burst into load->convert pairs (r9 pathology, VGPR=40).
  if (active) {
    #pragma unroll
    for (int ks = 0; ks < 5; ++ks)
      asm volatile("" : "+v"(buf[ks][0]), "+v"(buf[ks][1]));
  }

  __syncthreads();
  if (!active) return;   // after the only barrier

  // per-wave constants (cache-hit loads)
  float gmv[4], btv[4], w2v[4];
  #pragma unroll
  for (int nt = 0; nt < 4; ++nt) {
    const int c = nt * 16 + cidx;
    gmv[nt] = gma[c]; btv[nt] = bta[c]; w2v[nt] = Wg2[c];
  }

  // ---- convert x to bf16 A-fragments
  short8 xf[5];
  #pragma unroll
  for (int ks = 0; ks < 5; ++ks) {
    short8 f;
    #pragma unroll
    for (int j = 0; j < 4; ++j) {
      f[j]     = bf16_of(buf[ks][0][j]);
      f[4 + j] = bf16_of(buf[ks][1][j]);
    }
    xf[ks] = f;
  }

  // ---- phase 1: h = x @ Wg1  [16 x 64]  (B-frags from L2/L3)
  const f32x4 vzero = {0.f, 0.f, 0.f, 0.f};
  f32x4 acc1[4];
  #pragma unroll
  for (int nt = 0; nt < 4; ++nt) acc1[nt] = vzero;

  #pragma unroll
  for (int ks = 0; ks < 5; ++ks) {
    short8 bg[4];
    #pragma unroll
    for (int nt = 0; nt < 4; ++nt)
      bg[nt] = *reinterpret_cast<const short8*>(wf + (ks * 4 + nt) * 512 + lane * 8);
    #pragma unroll
    for (int nt = 0; nt < 4; ++nt)
      acc1[nt] = __builtin_amdgcn_mfma_f32_16x16x32_bf16(
          xf[ks], bg[nt], acc1[nt], 0, 0, 0);
  }

  // ---- LayerNorm + relu + dot(Wg2) + sigmoid (C-fragment layout)
  float gate[4];
  {
    float s[4], q[4];
    #pragma unroll
    for (int r = 0; r < 4; ++r) {
      s[r] = 0.f; q[r] = 0.f;
      #pragma unroll
      for (int nt = 0; nt < 4; ++nt) {
        const float c = acc1[nt][r];
        s[r] += c; q[r] += c * c;
      }
    }
    #pragma unroll
    for (int m = 1; m < 16; m <<= 1)
      #pragma unroll
      for (int r = 0; r < 4; ++r) {
        s[r] += __shfl_xor(s[r], m, 64);
        q[r] += __shfl_xor(q[r], m, 64);
      }
    float p[4];
    #pragma unroll
    for (int r = 0; r < 4; ++r) {
      const float mu  = s[r] * (1.f / CH);
      const float var = q[r] * (1.f / CH) - mu * mu;
      const float rsd = rsqrtf(var + 1e-5f);
      float pp = 0.f;
      #pragma unroll
      for (int nt = 0; nt < 4; ++nt) {
        const float h = fmaxf((acc1[nt][r] - mu) * rsd * gmv[nt] + btv[nt], 0.f);
        pp += h * w2v[nt];
      }
      p[r] = pp;
    }
    #pragma unroll
    for (int m = 1; m < 16; m <<= 1)
      #pragma unroll
      for (int r = 0; r < 4; ++r) p[r] += __shfl_xor(p[r], m, 64);
    #pragma unroll
    for (int r = 0; r < 4; ++r) gate[r] = 1.f / (1.f + expf(-p[r]));
  }

  // ---- phase 2 in 4 nt-quarter slices: dual D/C accumulate, blend, store
  #pragma unroll
  for (int q = 0; q < 4; ++q) {
    f32x4 aD[2], aC[2];
    #pragma unroll
    for (int nt = 0; nt < 2; ++nt) { aD[nt] = vzero; aC[nt] = vzero; }

    #pragma unroll
    for (int ks = 0; ks < 5; ++ks) {
      short8 bg[2];
      #pragma unroll
      for (int nt = 0; nt < 2; ++nt)
        bg[nt] = *reinterpret_cast<const short8*>(
            &wlds[(ks * 8 + q * 2 + nt) * 512 + lane * 8]);
      if (ks < 2) {
        #pragma unroll
        for (int nt = 0; nt < 2; ++nt)
          aD[nt] = __builtin_amdgcn_mfma_f32_16x16x32_bf16(
              xf[ks], bg[nt], aD[nt], 0, 0, 0);
      } else {
        #pragma unroll
        for (int nt = 0; nt < 2; ++nt)
          aC[nt] = __builtin_amdgcn_mfma_f32_16x16x32_bf16(
              xf[ks], bg[nt], aC[nt], 0, 0, 0);
      }
    }

    {
      const size_t rowb = (size_t)r0 + kb * 4;
      #pragma unroll
      for (int nt = 0; nt < 2; ++nt) {
        #pragma unroll
        for (int r = 0; r < 4; ++r) {
          const float g = gate[r];
          const float o = fmaf(g, aD[nt][r] - aC[nt][r], aC[nt][r]);
          out[(rowb + r) * CF + (q * 2 + nt) * 16 + cidx] = o;
        }
      }
    }
  }
}

}  // namespace

extern "C" void kernel_launch(void* const* d_in, const int* in_sizes, int n_in,
                              void* d_out, int out_size, void* d_ws, size_t ws_size,
                              hipStream_t stream) {
  const float* xd  = (const float*)d_in[0];
  const float* xc  = (const float*)d_in[1];
  const float* Wd  = (const float*)d_in[2];
  const float* Wc  = (const float*)d_in[3];
  const float* Wg1 = (const float*)d_in[4];
  const float* gma = (const float*)d_in[5];
  const float* bta = (const float*)d_in[6];
  const float* Wg2 = (const float*)d_in[7];
  float* out = (float*)d_out;
  short* ws  = (short*)d_ws;   // needs 60 KB

  const int N = in_sizes[0] / CD;

  convert_weights<<<dim3(15), dim3(256), 0, stream>>>(Wd, Wc, Wg1, ws);

  const int nblk = (N + 127) / 128;   // 128 rows per 8-wave block
  gate_fusion_mfma<<<dim3(nblk), dim3(512), 0, stream>>>(
      xd, xc, gma, bta, Wg2, ws, out, N);
}